// Round 6
// baseline (288.135 us; speedup 1.0000x reference)
//
#include <hip/hip_runtime.h>
#include <math.h>

// Problem constants
constexpr int Bsz  = 64;
constexpr int Tseq = 256;
constexpr int Cdim = 384;
constexpr int Hh   = 6;
constexpr int HSd  = 64;
constexpr int Mrows = Bsz * Tseq;        // 16384
constexpr int Cffn  = 4 * Cdim;          // 1536
constexpr int Nqkv  = 3 * Cdim;          // 1152

typedef __attribute__((ext_vector_type(8))) short short8;  // 8 bf16 = 4 VGPRs
typedef __attribute__((ext_vector_type(4))) float f32x4;

// fp32 -> bf16 round-to-nearest-even
__device__ __forceinline__ ushort f2bf(float x) {
  union { float f; uint u; } a; a.f = x;
  uint r = a.u + 0x7fffu + ((a.u >> 16) & 1u);
  return (ushort)(r >> 16);
}

// Fast GELU (tanh form): x * z/(1+z), z = exp(2*0.7978845608*(x+0.044715 x^3)).
// Max |diff| vs exact-erf gelu ~3e-4 (<< 0.1 threshold). ~8 VALU ops vs ~25
// for erff. Clamp the exponent so z never overflows to inf (inf/inf = NaN).
__device__ __forceinline__ float gelu_fast(float x) {
  float t = x * x;
  float u = x * fmaf(0.044715f, t, 1.0f);
  float e = fminf(1.5957691216f * u, 80.f);
  float z = __expf(e);
  return x * (z / (1.0f + z));
}

// ---------------------------------------------------------------------------
// Fused prep: all weight transpose-casts (fp32 [R][S] -> bf16 [S][R]) + bias
// concat, one launch. Blocks 0..1727 = 32x32 transpose tiles; 1728..1732 bias.
// ---------------------------------------------------------------------------
__global__ __launch_bounds__(256) void prep_kernel(
    const float* __restrict__ Wq, const float* __restrict__ Wk,
    const float* __restrict__ Wv, const float* __restrict__ Wproj,
    const float* __restrict__ W1, const float* __restrict__ W2,
    const float* __restrict__ bq, const float* __restrict__ bk,
    const float* __restrict__ bv,
    ushort* __restrict__ WqkvT, ushort* __restrict__ WprojT,
    ushort* __restrict__ W1T, ushort* __restrict__ W2T,
    float* __restrict__ bqkv) {
  const int bid = blockIdx.x;
  if (bid >= 1728) {  // bias concat
    int i = (bid - 1728) * 256 + threadIdx.x;
    if (i < Nqkv)
      bqkv[i] = (i < 384) ? bq[i] : (i < 768) ? bk[i - 384] : bv[i - 768];
    return;
  }
  const int tx = threadIdx.x & 31, ty = threadIdx.x >> 5;  // 32 x 8
  const float* src; ushort* dst; int R, S, r0, s0;
  if (bid < 432) {           // Wq/Wk/Wv: [6][384][64] each -> rows of WqkvT
    int which = bid / 144, rem = bid % 144;
    const float* W = (which == 0) ? Wq : (which == 1) ? Wk : Wv;
    int bz = rem / 24, t = rem % 24;
    R = 384; S = 64;
    src = W + (size_t)bz * R * S;
    dst = WqkvT + (size_t)which * 384 * 384 + (size_t)bz * R * S;
    r0 = (t >> 1) * 32; s0 = (t & 1) * 32;
  } else if (bid < 576) {    // Wproj 384x384
    int rem = bid - 432; R = 384; S = 384; src = Wproj; dst = WprojT;
    r0 = (rem / 12) * 32; s0 = (rem % 12) * 32;
  } else if (bid < 1152) {   // W1 384x1536
    int rem = bid - 576; R = 384; S = 1536; src = W1; dst = W1T;
    r0 = (rem / 48) * 32; s0 = (rem % 48) * 32;
  } else {                   // W2 1536x384
    int rem = bid - 1152; R = 1536; S = 384; src = W2; dst = W2T;
    r0 = (rem / 12) * 32; s0 = (rem % 12) * 32;
  }
  __shared__ float t[32][33];
#pragma unroll
  for (int i = 0; i < 32; i += 8)
    t[ty + i][tx] = src[(size_t)(r0 + ty + i) * S + s0 + tx];
  __syncthreads();
#pragma unroll
  for (int i = 0; i < 32; i += 8)
    dst[(size_t)(s0 + ty + i) * R + r0 + tx] = f2bf(t[tx][ty + i]);
}

// ---------------------------------------------------------------------------
// LayerNorm: one wave per row of 384; 4 rows per block. bf16 output.
// ---------------------------------------------------------------------------
__global__ __launch_bounds__(256) void ln_kernel(
    const float* __restrict__ x, const float* __restrict__ w,
    const float* __restrict__ b, ushort* __restrict__ out, int nrows) {
  int row  = blockIdx.x * 4 + (threadIdx.x >> 6);
  int lane = threadIdx.x & 63;
  if (row >= nrows) return;
  const float* xr = x + (size_t)row * Cdim;
  float v[6];
  float s = 0.f;
#pragma unroll
  for (int i = 0; i < 6; ++i) { v[i] = xr[lane + 64 * i]; s += v[i]; }
#pragma unroll
  for (int off = 32; off > 0; off >>= 1) s += __shfl_xor(s, off, 64);
  float mean = s * (1.f / Cdim);
  float sq = 0.f;
#pragma unroll
  for (int i = 0; i < 6; ++i) { float d = v[i] - mean; sq += d * d; }
#pragma unroll
  for (int off = 32; off > 0; off >>= 1) sq += __shfl_xor(sq, off, 64);
  float rstd = rsqrtf(sq * (1.f / Cdim) + 1e-5f);
  ushort* orow = out + (size_t)row * Cdim;
#pragma unroll
  for (int i = 0; i < 6; ++i) {
    int c = lane + 64 * i;
    orow[c] = f2bf((v[i] - mean) * rstd * w[c] + b[c]);
  }
}

// ---------------------------------------------------------------------------
// bf16 MFMA GEMM: C[M,N] = epi(A[M,K] @ Bt[N,K]^T + bias). 128x128 tile,
// BK=32, 4 waves (2x2 of 64x64), 4x4 16x16 MFMAs per wave.
// LDS XOR-swizzle (R5): conflict-free fragment reads (verified: 2.36M -> 0).
// XCD swizzle (R6): gridDim.y==128 always; XCD k owns row-tiles [16k,16k+16)
// x all columns -> per-XCD L2 working set = A strip (1.6MB) + B (<=2.4MB)
// fits 4MB; was A fetched ~4x (FETCH 51.7MB vs 14MB ideal on FFN1).
// Nontemporal epilogue stores + residual loads keep streams out of L2.
// EPI: 0 = +bias -> bf16; 1 = +bias+res -> fp32; 2 = gelu -> bf16
//      3 = QKV split: Q,K,V each -> [BH][T][64] bf16 (coalesced)
// ---------------------------------------------------------------------------
template <int EPI>
__global__ __launch_bounds__(256) void mfma_gemm(
    const ushort* __restrict__ A, const ushort* __restrict__ Bt,
    const float* __restrict__ bias, const float* __restrict__ res,
    void* __restrict__ Cout, void* __restrict__ C2, void* __restrict__ C3,
    int M, int N, int K) {
  __shared__ ushort Als[128 * 32];
  __shared__ ushort Bls[128 * 32];
  const int tid = threadIdx.x;

  // XCD-aware remap (requires gridDim.y == 128; all call sites satisfy this)
  const int lid = blockIdx.y * gridDim.x + blockIdx.x;
  const int xcd = lid & 7, idx = lid >> 3;
  const int by = xcd * 16 + (idx & 15);
  const int bx = idx >> 4;
  const int m0 = by * 128, n0 = bx * 128;

  const int lane = tid & 63;
  const int w    = tid >> 6;
  const int wr   = (w >> 1) * 64;
  const int wc   = (w & 1) * 64;
  const int lm   = lane & 15;
  const int g    = lane >> 4;
  const int rq   = g * 4;

  const int c0 = tid, c1 = tid + 256;
  const int wbase = (tid & ~63) * 8;
  const int kcs = (((c0 & 3) ^ ((c0 >> 3) & 3)) * 8);  // staging swizzle
  const int kqs = (g ^ ((lm >> 1) & 3)) * 8;           // reader swizzle

  f32x4 acc[4][4] = {};

  for (int k0 = 0; k0 < K; k0 += 32) {
    const ushort* gA0 = A  + (size_t)(m0 + (c0 >> 2)) * K + k0 + kcs;
    const ushort* gA1 = A  + (size_t)(m0 + (c1 >> 2)) * K + k0 + kcs;
    const ushort* gB0 = Bt + (size_t)(n0 + (c0 >> 2)) * K + k0 + kcs;
    const ushort* gB1 = Bt + (size_t)(n0 + (c1 >> 2)) * K + k0 + kcs;
    __syncthreads();
    __builtin_amdgcn_global_load_lds(
        (const __attribute__((address_space(1))) uint*)gA0,
        (__attribute__((address_space(3))) uint*)(Als + wbase), 16, 0, 0);
    __builtin_amdgcn_global_load_lds(
        (const __attribute__((address_space(1))) uint*)gA1,
        (__attribute__((address_space(3))) uint*)(Als + wbase + 2048), 16, 0, 0);
    __builtin_amdgcn_global_load_lds(
        (const __attribute__((address_space(1))) uint*)gB0,
        (__attribute__((address_space(3))) uint*)(Bls + wbase), 16, 0, 0);
    __builtin_amdgcn_global_load_lds(
        (const __attribute__((address_space(1))) uint*)gB1,
        (__attribute__((address_space(3))) uint*)(Bls + wbase + 2048), 16, 0, 0);
    __syncthreads();

    short8 af[4], bf[4];
#pragma unroll
    for (int i = 0; i < 4; ++i)
      af[i] = *(const short8*)&Als[(wr + i * 16 + lm) * 32 + kqs];
#pragma unroll
    for (int j = 0; j < 4; ++j)
      bf[j] = *(const short8*)&Bls[(wc + j * 16 + lm) * 32 + kqs];
#pragma unroll
    for (int i = 0; i < 4; ++i)
#pragma unroll
      for (int j = 0; j < 4; ++j)
        acc[i][j] = __builtin_amdgcn_mfma_f32_16x16x32_bf16(af[i], bf[j],
                                                            acc[i][j], 0, 0, 0);
  }

  float bb[4];
#pragma unroll
  for (int j = 0; j < 4; ++j) bb[j] = bias[n0 + wc + j * 16 + lm];

#pragma unroll
  for (int i = 0; i < 4; ++i) {
#pragma unroll
    for (int r = 0; r < 4; ++r) {
      const int row = m0 + wr + i * 16 + rq + r;
      if (EPI == 1) {
        const float* resrow = res + (size_t)row * N + n0 + wc;
        float* crow = (float*)Cout + (size_t)row * N + n0 + wc;
#pragma unroll
        for (int j = 0; j < 4; ++j) {
          float rv = __builtin_nontemporal_load(resrow + j * 16 + lm);
          __builtin_nontemporal_store(acc[i][j][r] + bb[j] + rv,
                                      crow + j * 16 + lm);
        }
      } else if (EPI == 3) {
        const int bb_ = row >> 8, tt = row & 255;
#pragma unroll
        for (int j = 0; j < 4; ++j) {
          const int colb = n0 + wc + j * 16;
          const int sec = colb / 384, cc = colb % 384;
          const int hh = cc >> 6, db = (cc & 63) + lm;
          ushort* dstp = (sec == 0) ? (ushort*)Cout
                       : (sec == 1) ? (ushort*)C2 : (ushort*)C3;
          __builtin_nontemporal_store(
              f2bf(acc[i][j][r] + bb[j]),
              &dstp[((size_t)(bb_ * Hh + hh) * Tseq + tt) * HSd + db]);
        }
      } else {
        ushort* crow = (ushort*)Cout + (size_t)row * N + n0 + wc;
#pragma unroll
        for (int j = 0; j < 4; ++j) {
          float v = acc[i][j][r] + bb[j];
          if (EPI == 2) v = gelu_fast(v);
          __builtin_nontemporal_store(f2bf(v), crow + j * 16 + lm);
        }
      }
    }
  }
}

// ---------------------------------------------------------------------------
// MFMA flash attention. Block = (b*H+h, q-tile of 64 rows), 4 waves; wave w
// owns a 16-row Q strip. LDS stride 72 ushorts -> conflict-free frag reads.
// V transposed into LDS during staging. Output Oc bf16 [M][384] concat.
// ---------------------------------------------------------------------------
__global__ __launch_bounds__(256) void attn_kernel(
    const ushort* __restrict__ Qb, const ushort* __restrict__ Kb,
    const ushort* __restrict__ Vb, ushort* __restrict__ Oc) {
  __shared__ ushort Ks[64 * 72];     // [key][dim]
  __shared__ ushort Vt[64 * 72];     // [dim][key]
  __shared__ ushort Pl[4][16 * 72];  // per-wave P strip [row][key]
  const int bh = blockIdx.x, qt = blockIdx.y;
  const int b = bh / Hh, h = bh % Hh;
  const int tid = threadIdx.x;
  const int w = tid >> 6, lane = tid & 63;
  const int g = lane >> 4, n16 = lane & 15;

  const ushort* qrow = Qb + ((size_t)bh * Tseq + qt * 64 + w * 16 + n16) * HSd;
  short8 qf0 = *(const short8*)(qrow + g * 8);
  short8 qf1 = *(const short8*)(qrow + 32 + g * 8);

  f32x4 oacc[4] = {};
  float m_r[4], l_r[4];
#pragma unroll
  for (int r = 0; r < 4; ++r) { m_r[r] = -1e30f; l_r[r] = 0.f; }

  const int t0 = qt * 64 + w * 16 + g * 4;

  const ushort* Ksrc = Kb + (size_t)bh * Tseq * HSd;
  const ushort* Vsrc = Vb + (size_t)bh * Tseq * HSd;

  for (int st = 0; st <= qt; ++st) {
    __syncthreads();
    for (int c = tid; c < 512; c += 256) {
      int kr = c >> 3, kc = (c & 7) * 8;
      *(uint4*)&Ks[kr * 72 + kc] =
          *(const uint4*)&Ksrc[(size_t)(st * 64 + kr) * HSd + kc];
      int vr = c & 63, vc = (c >> 6) * 8;
      uint4 vv = *(const uint4*)&Vsrc[(size_t)(st * 64 + vr) * HSd + vc];
      const ushort* pv = (const ushort*)&vv;
#pragma unroll
      for (int i = 0; i < 8; ++i) Vt[(vc + i) * 72 + vr] = pv[i];
    }
    __syncthreads();

    f32x4 s[4];
#pragma unroll
    for (int ct = 0; ct < 4; ++ct) {
      short8 kf0 = *(const short8*)&Ks[(ct * 16 + n16) * 72 + g * 8];
      short8 kf1 = *(const short8*)&Ks[(ct * 16 + n16) * 72 + 32 + g * 8];
      f32x4 z = {};
      z = __builtin_amdgcn_mfma_f32_16x16x32_bf16(qf0, kf0, z, 0, 0, 0);
      z = __builtin_amdgcn_mfma_f32_16x16x32_bf16(qf1, kf1, z, 0, 0, 0);
      s[ct] = z;
    }

#pragma unroll
    for (int ct = 0; ct < 4; ++ct) {
      const int s_col = st * 64 + ct * 16 + n16;
#pragma unroll
      for (int r = 0; r < 4; ++r) {
        float v = s[ct][r] * 0.125f;
        s[ct][r] = (s_col > t0 + r) ? -1e30f : v;
      }
    }

#pragma unroll
    for (int r = 0; r < 4; ++r) {
      float m = fmaxf(fmaxf(s[0][r], s[1][r]), fmaxf(s[2][r], s[3][r]));
      m = fmaxf(m, __shfl_xor(m, 1, 64));
      m = fmaxf(m, __shfl_xor(m, 2, 64));
      m = fmaxf(m, __shfl_xor(m, 4, 64));
      m = fmaxf(m, __shfl_xor(m, 8, 64));
      float mnew = fmaxf(m_r[r], m);
      float alpha = __expf(m_r[r] - mnew);
      m_r[r] = mnew;
      float ssum = 0.f;
#pragma unroll
      for (int ct = 0; ct < 4; ++ct) {
        float p = __expf(s[ct][r] - mnew);
        s[ct][r] = p;
        ssum += p;
      }
      ssum += __shfl_xor(ssum, 1, 64);
      ssum += __shfl_xor(ssum, 2, 64);
      ssum += __shfl_xor(ssum, 4, 64);
      ssum += __shfl_xor(ssum, 8, 64);
      l_r[r] = l_r[r] * alpha + ssum;
#pragma unroll
      for (int j = 0; j < 4; ++j) oacc[j][r] *= alpha;
    }

    ushort* pw = &Pl[w][0];
#pragma unroll
    for (int ct = 0; ct < 4; ++ct)
#pragma unroll
      for (int r = 0; r < 4; ++r)
        pw[(g * 4 + r) * 72 + ct * 16 + n16] = f2bf(s[ct][r]);

    short8 pf0 = *(const short8*)&pw[n16 * 72 + g * 8];
    short8 pf1 = *(const short8*)&pw[n16 * 72 + 32 + g * 8];
#pragma unroll
    for (int j = 0; j < 4; ++j) {
      short8 vf0 = *(const short8*)&Vt[(j * 16 + n16) * 72 + g * 8];
      short8 vf1 = *(const short8*)&Vt[(j * 16 + n16) * 72 + 32 + g * 8];
      oacc[j] = __builtin_amdgcn_mfma_f32_16x16x32_bf16(pf0, vf0, oacc[j], 0, 0, 0);
      oacc[j] = __builtin_amdgcn_mfma_f32_16x16x32_bf16(pf1, vf1, oacc[j], 0, 0, 0);
    }
  }

  float inv[4];
#pragma unroll
  for (int r = 0; r < 4; ++r) inv[r] = 1.f / l_r[r];
  ushort* orow = Oc + ((size_t)(b * Tseq + qt * 64 + w * 16)) * Cdim + h * HSd;
#pragma unroll
  for (int j = 0; j < 4; ++j)
#pragma unroll
    for (int r = 0; r < 4; ++r)
      orow[(size_t)(g * 4 + r) * Cdim + j * 16 + n16] = f2bf(oacc[j][r] * inv[r]);
}

// ---------------------------------------------------------------------------
extern "C" void kernel_launch(void* const* d_in, const int* in_sizes, int n_in,
                              void* d_out, int out_size, void* d_ws, size_t ws_size,
                              hipStream_t stream) {
  const float* x      = (const float*)d_in[0];
  const float* ln1_w  = (const float*)d_in[1];
  const float* ln1_b  = (const float*)d_in[2];
  const float* Wq     = (const float*)d_in[3];
  const float* bq     = (const float*)d_in[4];
  const float* Wk     = (const float*)d_in[5];
  const float* bk     = (const float*)d_in[6];
  const float* Wv     = (const float*)d_in[7];
  const float* bv     = (const float*)d_in[8];
  const float* Wproj  = (const float*)d_in[9];
  const float* bproj  = (const float*)d_in[10];
  const float* ln2_w  = (const float*)d_in[11];
  const float* ln2_b  = (const float*)d_in[12];
  const float* W1     = (const float*)d_in[13];
  const float* b1     = (const float*)d_in[14];
  const float* W2     = (const float*)d_in[15];
  const float* b2     = (const float*)d_in[16];
  float* out = (float*)d_out;

  // Workspace layout (~117 MB)
  char* p = (char*)d_ws;
  ushort* h     = (ushort*)p;  p += (size_t)Mrows * Cdim * 2;   // reused as h2
  ushort* Qb    = (ushort*)p;                                    // 12.6 MB
  float*  x1    = (float*)p;   p += (size_t)Mrows * HSd * Hh * 2;  // aliases Qb+Kb
  ushort* Kb    = (ushort*)p;  p += (size_t)Mrows * HSd * Hh * 2;
  ushort* Vb    = (ushort*)p;  p += (size_t)Mrows * HSd * Hh * 2;
  ushort* Oc    = (ushort*)p;  p += (size_t)Mrows * Cdim * 2;
  ushort* g     = (ushort*)p;  p += (size_t)Mrows * Cffn * 2;
  ushort* WqkvT = (ushort*)p;  p += (size_t)Nqkv * Cdim * 2;
  ushort* WprojT= (ushort*)p;  p += (size_t)Cdim * Cdim * 2;
  ushort* W1T   = (ushort*)p;  p += (size_t)Cffn * Cdim * 2;
  ushort* W2T   = (ushort*)p;  p += (size_t)Cdim * Cffn * 2;
  float*  bqkv  = (float*)p;   p += (size_t)Nqkv * 4;
  ushort* h2 = h;

  dim3 blk(256);

  // 0. Fused weight prep (transpose-casts + bias concat), one launch
  prep_kernel<<<dim3(1733), blk, 0, stream>>>(Wq, Wk, Wv, Wproj, W1, W2,
                                              bq, bk, bv,
                                              WqkvT, WprojT, W1T, W2T, bqkv);

  // 1. LN1 -> h (bf16)
  ln_kernel<<<dim3(Mrows / 4), blk, 0, stream>>>(x, ln1_w, ln1_b, h, Mrows);

  // 2. QKV fused GEMM, epilogue splits Q/K/V into [BH][T][64] (coalesced)
  mfma_gemm<3><<<dim3(Nqkv / 128, Mrows / 128), blk, 0, stream>>>(
      h, WqkvT, bqkv, nullptr, Qb, Kb, Vb, Mrows, Nqkv, Cdim);

  // 3. MFMA flash attention -> Oc (bf16, concat layout)
  attn_kernel<<<dim3(Bsz * Hh, 4), blk, 0, stream>>>(Qb, Kb, Vb, Oc);

  // 4. x1 = x + Oc @ Wproj + bproj (fp32)
  mfma_gemm<1><<<dim3(Cdim / 128, Mrows / 128), blk, 0, stream>>>(
      Oc, WprojT, bproj, x, x1, nullptr, nullptr, Mrows, Cdim, Cdim);

  // 5. LN2 -> h2 (bf16)
  ln_kernel<<<dim3(Mrows / 4), blk, 0, stream>>>(x1, ln2_w, ln2_b, h2, Mrows);

  // 6. g = gelu(h2 @ W1 + b1) (bf16)
  mfma_gemm<2><<<dim3(Cffn / 128, Mrows / 128), blk, 0, stream>>>(
      h2, W1T, b1, nullptr, g, nullptr, nullptr, Mrows, Cffn, Cdim);

  // 7. out = x1 + g @ W2 + b2 (fp32)
  mfma_gemm<1><<<dim3(Cdim / 128, Mrows / 128), blk, 0, stream>>>(
      g, W2T, b2, x1, out, nullptr, nullptr, Mrows, Cdim, Cffn);
}

// Round 7
// 267.224 us; speedup vs baseline: 1.0783x; 1.0783x over previous
//
#include <hip/hip_runtime.h>
#include <math.h>

// Problem constants
constexpr int Bsz  = 64;
constexpr int Tseq = 256;
constexpr int Cdim = 384;
constexpr int Hh   = 6;
constexpr int HSd  = 64;
constexpr int Mrows = Bsz * Tseq;        // 16384
constexpr int Cffn  = 4 * Cdim;          // 1536
constexpr int Nqkv  = 3 * Cdim;          // 1152

typedef __attribute__((ext_vector_type(8))) short short8;  // 8 bf16 = 4 VGPRs
typedef __attribute__((ext_vector_type(4))) float f32x4;

// fp32 -> bf16 round-to-nearest-even
__device__ __forceinline__ ushort f2bf(float x) {
  union { float f; uint u; } a; a.f = x;
  uint r = a.u + 0x7fffu + ((a.u >> 16) & 1u);
  return (ushort)(r >> 16);
}

// Fast GELU (tanh form): ~3e-4 max error vs exact-erf, ~8 VALU ops vs ~25.
__device__ __forceinline__ float gelu_fast(float x) {
  float t = x * x;
  float u = x * fmaf(0.044715f, t, 1.0f);
  float e = fminf(1.5957691216f * u, 80.f);
  float z = __expf(e);
  return x * (z / (1.0f + z));
}

// ---------------------------------------------------------------------------
// Fused prep: all weight transpose-casts (fp32 [R][S] -> bf16 [S][R]) + bias
// concat, one launch. Blocks 0..1727 = 32x32 transpose tiles; 1728..1732 bias.
// ---------------------------------------------------------------------------
__global__ __launch_bounds__(256) void prep_kernel(
    const float* __restrict__ Wq, const float* __restrict__ Wk,
    const float* __restrict__ Wv, const float* __restrict__ Wproj,
    const float* __restrict__ W1, const float* __restrict__ W2,
    const float* __restrict__ bq, const float* __restrict__ bk,
    const float* __restrict__ bv,
    ushort* __restrict__ WqkvT, ushort* __restrict__ WprojT,
    ushort* __restrict__ W1T, ushort* __restrict__ W2T,
    float* __restrict__ bqkv) {
  const int bid = blockIdx.x;
  if (bid >= 1728) {  // bias concat
    int i = (bid - 1728) * 256 + threadIdx.x;
    if (i < Nqkv)
      bqkv[i] = (i < 384) ? bq[i] : (i < 768) ? bk[i - 384] : bv[i - 768];
    return;
  }
  const int tx = threadIdx.x & 31, ty = threadIdx.x >> 5;  // 32 x 8
  const float* src; ushort* dst; int R, S, r0, s0;
  if (bid < 432) {           // Wq/Wk/Wv: [6][384][64] each -> rows of WqkvT
    int which = bid / 144, rem = bid % 144;
    const float* W = (which == 0) ? Wq : (which == 1) ? Wk : Wv;
    int bz = rem / 24, t = rem % 24;
    R = 384; S = 64;
    src = W + (size_t)bz * R * S;
    dst = WqkvT + (size_t)which * 384 * 384 + (size_t)bz * R * S;
    r0 = (t >> 1) * 32; s0 = (t & 1) * 32;
  } else if (bid < 576) {    // Wproj 384x384
    int rem = bid - 432; R = 384; S = 384; src = Wproj; dst = WprojT;
    r0 = (rem / 12) * 32; s0 = (rem % 12) * 32;
  } else if (bid < 1152) {   // W1 384x1536
    int rem = bid - 576; R = 384; S = 1536; src = W1; dst = W1T;
    r0 = (rem / 48) * 32; s0 = (rem % 48) * 32;
  } else {                   // W2 1536x384
    int rem = bid - 1152; R = 1536; S = 384; src = W2; dst = W2T;
    r0 = (rem / 12) * 32; s0 = (rem % 12) * 32;
  }
  __shared__ float t[32][33];
#pragma unroll
  for (int i = 0; i < 32; i += 8)
    t[ty + i][tx] = src[(size_t)(r0 + ty + i) * S + s0 + tx];
  __syncthreads();
#pragma unroll
  for (int i = 0; i < 32; i += 8)
    dst[(size_t)(s0 + ty + i) * R + r0 + tx] = f2bf(t[tx][ty + i]);
}

// ---------------------------------------------------------------------------
// LayerNorm: one wave per row of 384; 4 rows per block. bf16 output.
// ---------------------------------------------------------------------------
__global__ __launch_bounds__(256) void ln_kernel(
    const float* __restrict__ x, const float* __restrict__ w,
    const float* __restrict__ b, ushort* __restrict__ out, int nrows) {
  int row  = blockIdx.x * 4 + (threadIdx.x >> 6);
  int lane = threadIdx.x & 63;
  if (row >= nrows) return;
  const float* xr = x + (size_t)row * Cdim;
  float v[6];
  float s = 0.f;
#pragma unroll
  for (int i = 0; i < 6; ++i) { v[i] = xr[lane + 64 * i]; s += v[i]; }
#pragma unroll
  for (int off = 32; off > 0; off >>= 1) s += __shfl_xor(s, off, 64);
  float mean = s * (1.f / Cdim);
  float sq = 0.f;
#pragma unroll
  for (int i = 0; i < 6; ++i) { float d = v[i] - mean; sq += d * d; }
#pragma unroll
  for (int off = 32; off > 0; off >>= 1) sq += __shfl_xor(sq, off, 64);
  float rstd = rsqrtf(sq * (1.f / Cdim) + 1e-5f);
  ushort* orow = out + (size_t)row * Cdim;
#pragma unroll
  for (int i = 0; i < 6; ++i) {
    int c = lane + 64 * i;
    orow[c] = f2bf((v[i] - mean) * rstd * w[c] + b[c]);
  }
}

// ---------------------------------------------------------------------------
// bf16 MFMA GEMM: C[M,N] = epi(A[M,K] @ Bt[N,K]^T + bias). 128x128 tile,
// BK=32, 4 waves (2x2 of 64x64), 4x4 16x16 MFMAs per wave.
// LDS XOR-swizzle (R5): conflict-free fragment reads (2.36M -> 0 verified).
// XCD swizzle (R6): FETCH 51.7 -> 10.9 MB verified. gridDim.y==128 required.
// NO nontemporal stores (R6 lesson: nt on 2-byte stores defeats L2 write
// combining -> 2.2x write amplification, 49 -> 109 MB). nt loads on the
// stream-once residual are kept (loads can't amplify writes).
// EPI: 0 = +bias -> bf16; 1 = +bias+res -> fp32; 2 = gelu -> bf16
//      3 = QKV split: Q,K,V each -> [BH][T][64] bf16 (coalesced)
// ---------------------------------------------------------------------------
template <int EPI>
__global__ __launch_bounds__(256) void mfma_gemm(
    const ushort* __restrict__ A, const ushort* __restrict__ Bt,
    const float* __restrict__ bias, const float* __restrict__ res,
    void* __restrict__ Cout, void* __restrict__ C2, void* __restrict__ C3,
    int M, int N, int K) {
  __shared__ ushort Als[128 * 32];
  __shared__ ushort Bls[128 * 32];
  const int tid = threadIdx.x;

  // XCD-aware remap (requires gridDim.y == 128; all call sites satisfy this)
  const int lid = blockIdx.y * gridDim.x + blockIdx.x;
  const int xcd = lid & 7, idx = lid >> 3;
  const int by = xcd * 16 + (idx & 15);
  const int bx = idx >> 4;
  const int m0 = by * 128, n0 = bx * 128;

  const int lane = tid & 63;
  const int w    = tid >> 6;
  const int wr   = (w >> 1) * 64;
  const int wc   = (w & 1) * 64;
  const int lm   = lane & 15;
  const int g    = lane >> 4;
  const int rq   = g * 4;

  const int c0 = tid, c1 = tid + 256;
  const int wbase = (tid & ~63) * 8;
  const int kcs = (((c0 & 3) ^ ((c0 >> 3) & 3)) * 8);  // staging swizzle
  const int kqs = (g ^ ((lm >> 1) & 3)) * 8;           // reader swizzle

  f32x4 acc[4][4] = {};

  for (int k0 = 0; k0 < K; k0 += 32) {
    const ushort* gA0 = A  + (size_t)(m0 + (c0 >> 2)) * K + k0 + kcs;
    const ushort* gA1 = A  + (size_t)(m0 + (c1 >> 2)) * K + k0 + kcs;
    const ushort* gB0 = Bt + (size_t)(n0 + (c0 >> 2)) * K + k0 + kcs;
    const ushort* gB1 = Bt + (size_t)(n0 + (c1 >> 2)) * K + k0 + kcs;
    __syncthreads();
    __builtin_amdgcn_global_load_lds(
        (const __attribute__((address_space(1))) uint*)gA0,
        (__attribute__((address_space(3))) uint*)(Als + wbase), 16, 0, 0);
    __builtin_amdgcn_global_load_lds(
        (const __attribute__((address_space(1))) uint*)gA1,
        (__attribute__((address_space(3))) uint*)(Als + wbase + 2048), 16, 0, 0);
    __builtin_amdgcn_global_load_lds(
        (const __attribute__((address_space(1))) uint*)gB0,
        (__attribute__((address_space(3))) uint*)(Bls + wbase), 16, 0, 0);
    __builtin_amdgcn_global_load_lds(
        (const __attribute__((address_space(1))) uint*)gB1,
        (__attribute__((address_space(3))) uint*)(Bls + wbase + 2048), 16, 0, 0);
    __syncthreads();

    short8 af[4], bf[4];
#pragma unroll
    for (int i = 0; i < 4; ++i)
      af[i] = *(const short8*)&Als[(wr + i * 16 + lm) * 32 + kqs];
#pragma unroll
    for (int j = 0; j < 4; ++j)
      bf[j] = *(const short8*)&Bls[(wc + j * 16 + lm) * 32 + kqs];
#pragma unroll
    for (int i = 0; i < 4; ++i)
#pragma unroll
      for (int j = 0; j < 4; ++j)
        acc[i][j] = __builtin_amdgcn_mfma_f32_16x16x32_bf16(af[i], bf[j],
                                                            acc[i][j], 0, 0, 0);
  }

  float bb[4];
#pragma unroll
  for (int j = 0; j < 4; ++j) bb[j] = bias[n0 + wc + j * 16 + lm];

#pragma unroll
  for (int i = 0; i < 4; ++i) {
#pragma unroll
    for (int r = 0; r < 4; ++r) {
      const int row = m0 + wr + i * 16 + rq + r;
      if (EPI == 1) {
        const float* resrow = res + (size_t)row * N + n0 + wc;
        float* crow = (float*)Cout + (size_t)row * N + n0 + wc;
#pragma unroll
        for (int j = 0; j < 4; ++j) {
          float rv = __builtin_nontemporal_load(resrow + j * 16 + lm);
          crow[j * 16 + lm] = acc[i][j][r] + bb[j] + rv;
        }
      } else if (EPI == 3) {
        const int bb_ = row >> 8, tt = row & 255;
#pragma unroll
        for (int j = 0; j < 4; ++j) {
          const int colb = n0 + wc + j * 16;
          const int sec = colb / 384, cc = colb % 384;
          const int hh = cc >> 6, db = (cc & 63) + lm;
          ushort* dstp = (sec == 0) ? (ushort*)Cout
                       : (sec == 1) ? (ushort*)C2 : (ushort*)C3;
          dstp[((size_t)(bb_ * Hh + hh) * Tseq + tt) * HSd + db] =
              f2bf(acc[i][j][r] + bb[j]);
        }
      } else {
        ushort* crow = (ushort*)Cout + (size_t)row * N + n0 + wc;
#pragma unroll
        for (int j = 0; j < 4; ++j) {
          float v = acc[i][j][r] + bb[j];
          if (EPI == 2) v = gelu_fast(v);
          crow[j * 16 + lm] = f2bf(v);
        }
      }
    }
  }
}

// ---------------------------------------------------------------------------
// MFMA flash attention. Block = (b*H+h, q-tile of 64 rows), 4 waves; wave w
// owns a 16-row Q strip. LDS stride 72 ushorts -> conflict-free frag reads.
// V transposed into LDS during staging. Output Oc bf16 [M][384] concat.
// ---------------------------------------------------------------------------
__global__ __launch_bounds__(256) void attn_kernel(
    const ushort* __restrict__ Qb, const ushort* __restrict__ Kb,
    const ushort* __restrict__ Vb, ushort* __restrict__ Oc) {
  __shared__ ushort Ks[64 * 72];     // [key][dim]
  __shared__ ushort Vt[64 * 72];     // [dim][key]
  __shared__ ushort Pl[4][16 * 72];  // per-wave P strip [row][key]
  const int bh = blockIdx.x, qt = blockIdx.y;
  const int b = bh / Hh, h = bh % Hh;
  const int tid = threadIdx.x;
  const int w = tid >> 6, lane = tid & 63;
  const int g = lane >> 4, n16 = lane & 15;

  const ushort* qrow = Qb + ((size_t)bh * Tseq + qt * 64 + w * 16 + n16) * HSd;
  short8 qf0 = *(const short8*)(qrow + g * 8);
  short8 qf1 = *(const short8*)(qrow + 32 + g * 8);

  f32x4 oacc[4] = {};
  float m_r[4], l_r[4];
#pragma unroll
  for (int r = 0; r < 4; ++r) { m_r[r] = -1e30f; l_r[r] = 0.f; }

  const int t0 = qt * 64 + w * 16 + g * 4;

  const ushort* Ksrc = Kb + (size_t)bh * Tseq * HSd;
  const ushort* Vsrc = Vb + (size_t)bh * Tseq * HSd;

  for (int st = 0; st <= qt; ++st) {
    __syncthreads();
    for (int c = tid; c < 512; c += 256) {
      int kr = c >> 3, kc = (c & 7) * 8;
      *(uint4*)&Ks[kr * 72 + kc] =
          *(const uint4*)&Ksrc[(size_t)(st * 64 + kr) * HSd + kc];
      int vr = c & 63, vc = (c >> 6) * 8;
      uint4 vv = *(const uint4*)&Vsrc[(size_t)(st * 64 + vr) * HSd + vc];
      const ushort* pv = (const ushort*)&vv;
#pragma unroll
      for (int i = 0; i < 8; ++i) Vt[(vc + i) * 72 + vr] = pv[i];
    }
    __syncthreads();

    f32x4 s[4];
#pragma unroll
    for (int ct = 0; ct < 4; ++ct) {
      short8 kf0 = *(const short8*)&Ks[(ct * 16 + n16) * 72 + g * 8];
      short8 kf1 = *(const short8*)&Ks[(ct * 16 + n16) * 72 + 32 + g * 8];
      f32x4 z = {};
      z = __builtin_amdgcn_mfma_f32_16x16x32_bf16(qf0, kf0, z, 0, 0, 0);
      z = __builtin_amdgcn_mfma_f32_16x16x32_bf16(qf1, kf1, z, 0, 0, 0);
      s[ct] = z;
    }

#pragma unroll
    for (int ct = 0; ct < 4; ++ct) {
      const int s_col = st * 64 + ct * 16 + n16;
#pragma unroll
      for (int r = 0; r < 4; ++r) {
        float v = s[ct][r] * 0.125f;
        s[ct][r] = (s_col > t0 + r) ? -1e30f : v;
      }
    }

#pragma unroll
    for (int r = 0; r < 4; ++r) {
      float m = fmaxf(fmaxf(s[0][r], s[1][r]), fmaxf(s[2][r], s[3][r]));
      m = fmaxf(m, __shfl_xor(m, 1, 64));
      m = fmaxf(m, __shfl_xor(m, 2, 64));
      m = fmaxf(m, __shfl_xor(m, 4, 64));
      m = fmaxf(m, __shfl_xor(m, 8, 64));
      float mnew = fmaxf(m_r[r], m);
      float alpha = __expf(m_r[r] - mnew);
      m_r[r] = mnew;
      float ssum = 0.f;
#pragma unroll
      for (int ct = 0; ct < 4; ++ct) {
        float p = __expf(s[ct][r] - mnew);
        s[ct][r] = p;
        ssum += p;
      }
      ssum += __shfl_xor(ssum, 1, 64);
      ssum += __shfl_xor(ssum, 2, 64);
      ssum += __shfl_xor(ssum, 4, 64);
      ssum += __shfl_xor(ssum, 8, 64);
      l_r[r] = l_r[r] * alpha + ssum;
#pragma unroll
      for (int j = 0; j < 4; ++j) oacc[j][r] *= alpha;
    }

    ushort* pw = &Pl[w][0];
#pragma unroll
    for (int ct = 0; ct < 4; ++ct)
#pragma unroll
      for (int r = 0; r < 4; ++r)
        pw[(g * 4 + r) * 72 + ct * 16 + n16] = f2bf(s[ct][r]);

    short8 pf0 = *(const short8*)&pw[n16 * 72 + g * 8];
    short8 pf1 = *(const short8*)&pw[n16 * 72 + 32 + g * 8];
#pragma unroll
    for (int j = 0; j < 4; ++j) {
      short8 vf0 = *(const short8*)&Vt[(j * 16 + n16) * 72 + g * 8];
      short8 vf1 = *(const short8*)&Vt[(j * 16 + n16) * 72 + 32 + g * 8];
      oacc[j] = __builtin_amdgcn_mfma_f32_16x16x32_bf16(pf0, vf0, oacc[j], 0, 0, 0);
      oacc[j] = __builtin_amdgcn_mfma_f32_16x16x32_bf16(pf1, vf1, oacc[j], 0, 0, 0);
    }
  }

  float inv[4];
#pragma unroll
  for (int r = 0; r < 4; ++r) inv[r] = 1.f / l_r[r];
  ushort* orow = Oc + ((size_t)(b * Tseq + qt * 64 + w * 16)) * Cdim + h * HSd;
#pragma unroll
  for (int j = 0; j < 4; ++j)
#pragma unroll
    for (int r = 0; r < 4; ++r)
      orow[(size_t)(g * 4 + r) * Cdim + j * 16 + n16] = f2bf(oacc[j][r] * inv[r]);
}

// ---------------------------------------------------------------------------
extern "C" void kernel_launch(void* const* d_in, const int* in_sizes, int n_in,
                              void* d_out, int out_size, void* d_ws, size_t ws_size,
                              hipStream_t stream) {
  const float* x      = (const float*)d_in[0];
  const float* ln1_w  = (const float*)d_in[1];
  const float* ln1_b  = (const float*)d_in[2];
  const float* Wq     = (const float*)d_in[3];
  const float* bq     = (const float*)d_in[4];
  const float* Wk     = (const float*)d_in[5];
  const float* bk     = (const float*)d_in[6];
  const float* Wv     = (const float*)d_in[7];
  const float* bv     = (const float*)d_in[8];
  const float* Wproj  = (const float*)d_in[9];
  const float* bproj  = (const float*)d_in[10];
  const float* ln2_w  = (const float*)d_in[11];
  const float* ln2_b  = (const float*)d_in[12];
  const float* W1     = (const float*)d_in[13];
  const float* b1     = (const float*)d_in[14];
  const float* W2     = (const float*)d_in[15];
  const float* b2     = (const float*)d_in[16];
  float* out = (float*)d_out;

  // Workspace layout (~117 MB)
  char* p = (char*)d_ws;
  ushort* h     = (ushort*)p;  p += (size_t)Mrows * Cdim * 2;   // reused as h2
  ushort* Qb    = (ushort*)p;                                    // 12.6 MB
  float*  x1    = (float*)p;   p += (size_t)Mrows * HSd * Hh * 2;  // aliases Qb+Kb
  ushort* Kb    = (ushort*)p;  p += (size_t)Mrows * HSd * Hh * 2;
  ushort* Vb    = (ushort*)p;  p += (size_t)Mrows * HSd * Hh * 2;
  ushort* Oc    = (ushort*)p;  p += (size_t)Mrows * Cdim * 2;
  ushort* g     = (ushort*)p;  p += (size_t)Mrows * Cffn * 2;
  ushort* WqkvT = (ushort*)p;  p += (size_t)Nqkv * Cdim * 2;
  ushort* WprojT= (ushort*)p;  p += (size_t)Cdim * Cdim * 2;
  ushort* W1T   = (ushort*)p;  p += (size_t)Cffn * Cdim * 2;
  ushort* W2T   = (ushort*)p;  p += (size_t)Cdim * Cffn * 2;
  float*  bqkv  = (float*)p;   p += (size_t)Nqkv * 4;
  ushort* h2 = h;

  dim3 blk(256);

  // 0. Fused weight prep (transpose-casts + bias concat), one launch
  prep_kernel<<<dim3(1733), blk, 0, stream>>>(Wq, Wk, Wv, Wproj, W1, W2,
                                              bq, bk, bv,
                                              WqkvT, WprojT, W1T, W2T, bqkv);

  // 1. LN1 -> h (bf16)
  ln_kernel<<<dim3(Mrows / 4), blk, 0, stream>>>(x, ln1_w, ln1_b, h, Mrows);

  // 2. QKV fused GEMM, epilogue splits Q/K/V into [BH][T][64] (coalesced)
  mfma_gemm<3><<<dim3(Nqkv / 128, Mrows / 128), blk, 0, stream>>>(
      h, WqkvT, bqkv, nullptr, Qb, Kb, Vb, Mrows, Nqkv, Cdim);

  // 3. MFMA flash attention -> Oc (bf16, concat layout)
  attn_kernel<<<dim3(Bsz * Hh, 4), blk, 0, stream>>>(Qb, Kb, Vb, Oc);

  // 4. x1 = x + Oc @ Wproj + bproj (fp32)
  mfma_gemm<1><<<dim3(Cdim / 128, Mrows / 128), blk, 0, stream>>>(
      Oc, WprojT, bproj, x, x1, nullptr, nullptr, Mrows, Cdim, Cdim);

  // 5. LN2 -> h2 (bf16)
  ln_kernel<<<dim3(Mrows / 4), blk, 0, stream>>>(x1, ln2_w, ln2_b, h2, Mrows);

  // 6. g = gelu(h2 @ W1 + b1) (bf16)
  mfma_gemm<2><<<dim3(Cffn / 128, Mrows / 128), blk, 0, stream>>>(
      h2, W1T, b1, nullptr, g, nullptr, nullptr, Mrows, Cffn, Cdim);

  // 7. out = x1 + g @ W2 + b2 (fp32)
  mfma_gemm<1><<<dim3(Cdim / 128, Mrows / 128), blk, 0, stream>>>(
      g, W2T, b2, x1, out, nullptr, nullptr, Mrows, Cdim, Cffn);
}

// Round 8
// 262.652 us; speedup vs baseline: 1.0970x; 1.0174x over previous
//
#include <hip/hip_runtime.h>
#include <math.h>

// Problem constants
constexpr int Bsz  = 64;
constexpr int Tseq = 256;
constexpr int Cdim = 384;
constexpr int Hh   = 6;
constexpr int HSd  = 64;
constexpr int Mrows = Bsz * Tseq;        // 16384
constexpr int Cffn  = 4 * Cdim;          // 1536
constexpr int Nqkv  = 3 * Cdim;          // 1152

typedef __attribute__((ext_vector_type(8))) short short8;  // 8 bf16 = 4 VGPRs
typedef __attribute__((ext_vector_type(4))) float f32x4;

// fp32 -> bf16 round-to-nearest-even
__device__ __forceinline__ ushort f2bf(float x) {
  union { float f; uint u; } a; a.f = x;
  uint r = a.u + 0x7fffu + ((a.u >> 16) & 1u);
  return (ushort)(r >> 16);
}

// Fast GELU (tanh form): ~3e-4 max error vs exact-erf, ~8 VALU ops vs ~25.
__device__ __forceinline__ float gelu_fast(float x) {
  float t = x * x;
  float u = x * fmaf(0.044715f, t, 1.0f);
  float e = fminf(1.5957691216f * u, 80.f);
  float z = __expf(e);
  return x * (z / (1.0f + z));
}

// ---------------------------------------------------------------------------
// Fused prep: all weight transpose-casts (fp32 [R][S] -> bf16 [S][R]) + bias
// concat, one launch. Blocks 0..1727 = 32x32 transpose tiles; 1728..1732 bias.
// ---------------------------------------------------------------------------
__global__ __launch_bounds__(256) void prep_kernel(
    const float* __restrict__ Wq, const float* __restrict__ Wk,
    const float* __restrict__ Wv, const float* __restrict__ Wproj,
    const float* __restrict__ W1, const float* __restrict__ W2,
    const float* __restrict__ bq, const float* __restrict__ bk,
    const float* __restrict__ bv,
    ushort* __restrict__ WqkvT, ushort* __restrict__ WprojT,
    ushort* __restrict__ W1T, ushort* __restrict__ W2T,
    float* __restrict__ bqkv) {
  const int bid = blockIdx.x;
  if (bid >= 1728) {  // bias concat
    int i = (bid - 1728) * 256 + threadIdx.x;
    if (i < Nqkv)
      bqkv[i] = (i < 384) ? bq[i] : (i < 768) ? bk[i - 384] : bv[i - 768];
    return;
  }
  const int tx = threadIdx.x & 31, ty = threadIdx.x >> 5;  // 32 x 8
  const float* src; ushort* dst; int R, S, r0, s0;
  if (bid < 432) {           // Wq/Wk/Wv: [6][384][64] each -> rows of WqkvT
    int which = bid / 144, rem = bid % 144;
    const float* W = (which == 0) ? Wq : (which == 1) ? Wk : Wv;
    int bz = rem / 24, t = rem % 24;
    R = 384; S = 64;
    src = W + (size_t)bz * R * S;
    dst = WqkvT + (size_t)which * 384 * 384 + (size_t)bz * R * S;
    r0 = (t >> 1) * 32; s0 = (t & 1) * 32;
  } else if (bid < 576) {    // Wproj 384x384
    int rem = bid - 432; R = 384; S = 384; src = Wproj; dst = WprojT;
    r0 = (rem / 12) * 32; s0 = (rem % 12) * 32;
  } else if (bid < 1152) {   // W1 384x1536
    int rem = bid - 576; R = 384; S = 1536; src = W1; dst = W1T;
    r0 = (rem / 48) * 32; s0 = (rem % 48) * 32;
  } else {                   // W2 1536x384
    int rem = bid - 1152; R = 1536; S = 384; src = W2; dst = W2T;
    r0 = (rem / 12) * 32; s0 = (rem % 12) * 32;
  }
  __shared__ float t[32][33];
#pragma unroll
  for (int i = 0; i < 32; i += 8)
    t[ty + i][tx] = src[(size_t)(r0 + ty + i) * S + s0 + tx];
  __syncthreads();
#pragma unroll
  for (int i = 0; i < 32; i += 8)
    dst[(size_t)(s0 + ty + i) * R + r0 + tx] = f2bf(t[tx][ty + i]);
}

// ---------------------------------------------------------------------------
// LayerNorm: one wave per row of 384; 4 rows per block. bf16 output.
// ---------------------------------------------------------------------------
__global__ __launch_bounds__(256) void ln_kernel(
    const float* __restrict__ x, const float* __restrict__ w,
    const float* __restrict__ b, ushort* __restrict__ out, int nrows) {
  int row  = blockIdx.x * 4 + (threadIdx.x >> 6);
  int lane = threadIdx.x & 63;
  if (row >= nrows) return;
  const float* xr = x + (size_t)row * Cdim;
  float v[6];
  float s = 0.f;
#pragma unroll
  for (int i = 0; i < 6; ++i) { v[i] = xr[lane + 64 * i]; s += v[i]; }
#pragma unroll
  for (int off = 32; off > 0; off >>= 1) s += __shfl_xor(s, off, 64);
  float mean = s * (1.f / Cdim);
  float sq = 0.f;
#pragma unroll
  for (int i = 0; i < 6; ++i) { float d = v[i] - mean; sq += d * d; }
#pragma unroll
  for (int off = 32; off > 0; off >>= 1) sq += __shfl_xor(sq, off, 64);
  float rstd = rsqrtf(sq * (1.f / Cdim) + 1e-5f);
  ushort* orow = out + (size_t)row * Cdim;
#pragma unroll
  for (int i = 0; i < 6; ++i) {
    int c = lane + 64 * i;
    orow[c] = f2bf((v[i] - mean) * rstd * w[c] + b[c]);
  }
}

// ---------------------------------------------------------------------------
// bf16 MFMA GEMM: C[M,N] = epi(A[M,K] @ Bt[N,K]^T + bias). 128xBN tile,
// BK=32, 4 waves (2x2), wave tile 64 x BN/2.
// BN=128 for fat GEMMs (N>=1152); BN=64 for skinny N=384 GEMMs -> 768 blocks
// = 3 blocks/CU so the barrier vmcnt drain is covered by other blocks' waves
// (R7 lesson: at 1-2 blocks/CU the skinny GEMMs were latency-bound, occ 12%).
// LDS XOR-swizzle (R5): conflict-free fragment reads (2.36M -> 0 verified).
// XCD swizzle (R6): FETCH 51.7 -> 10.9 MB verified. gridDim.y==128 required.
// No nontemporal stores (R6: nt + 2-byte stores -> 2.2x write amplification).
// EPI: 0 = +bias -> bf16; 1 = +bias+res -> fp32; 2 = gelu -> bf16
//      3 = QKV split: Q,K,V each -> [BH][T][64] bf16 (BN=128 only)
// ---------------------------------------------------------------------------
template <int EPI, int BN>
__global__ __launch_bounds__(256) void mfma_gemm(
    const ushort* __restrict__ A, const ushort* __restrict__ Bt,
    const float* __restrict__ bias, const float* __restrict__ res,
    void* __restrict__ Cout, void* __restrict__ C2, void* __restrict__ C3,
    int M, int N, int K) {
  constexpr int WC = BN / 2;    // wave col span
  constexpr int JN = WC / 16;   // col frags per wave (4 or 2)
  __shared__ ushort Als[128 * 32];
  __shared__ ushort Bls[BN * 32];
  const int tid = threadIdx.x;

  // XCD-aware remap (requires gridDim.y == 128; per-XCD: 16 row-strips x all
  // col-blocks). Valid for any gridDim.x.
  const int lid = blockIdx.y * gridDim.x + blockIdx.x;
  const int xcd = lid & 7, idx = lid >> 3;
  const int by = xcd * 16 + (idx & 15);
  const int bx = idx >> 4;
  const int m0 = by * 128, n0 = bx * BN;

  const int lane = tid & 63;
  const int w    = tid >> 6;
  const int wr   = (w >> 1) * 64;
  const int wc   = (w & 1) * WC;
  const int lm   = lane & 15;
  const int g    = lane >> 4;
  const int rq   = g * 4;

  const int c0 = tid, c1 = tid + 256;
  const int wbase = (tid & ~63) * 8;
  const int kcs = (((c0 & 3) ^ ((c0 >> 3) & 3)) * 8);  // staging swizzle
  const int kqs = (g ^ ((lm >> 1) & 3)) * 8;           // reader swizzle

  f32x4 acc[4][JN] = {};

  for (int k0 = 0; k0 < K; k0 += 32) {
    const ushort* gA0 = A  + (size_t)(m0 + (c0 >> 2)) * K + k0 + kcs;
    const ushort* gA1 = A  + (size_t)(m0 + (c1 >> 2)) * K + k0 + kcs;
    const ushort* gB0 = Bt + (size_t)(n0 + (c0 >> 2)) * K + k0 + kcs;
    __syncthreads();
    __builtin_amdgcn_global_load_lds(
        (const __attribute__((address_space(1))) uint*)gA0,
        (__attribute__((address_space(3))) uint*)(Als + wbase), 16, 0, 0);
    __builtin_amdgcn_global_load_lds(
        (const __attribute__((address_space(1))) uint*)gA1,
        (__attribute__((address_space(3))) uint*)(Als + wbase + 2048), 16, 0, 0);
    __builtin_amdgcn_global_load_lds(
        (const __attribute__((address_space(1))) uint*)gB0,
        (__attribute__((address_space(3))) uint*)(Bls + wbase), 16, 0, 0);
    if constexpr (BN == 128) {
      const ushort* gB1 = Bt + (size_t)(n0 + (c1 >> 2)) * K + k0 + kcs;
      __builtin_amdgcn_global_load_lds(
          (const __attribute__((address_space(1))) uint*)gB1,
          (__attribute__((address_space(3))) uint*)(Bls + wbase + 2048), 16, 0, 0);
    }
    __syncthreads();

    short8 af[4], bf[JN];
#pragma unroll
    for (int i = 0; i < 4; ++i)
      af[i] = *(const short8*)&Als[(wr + i * 16 + lm) * 32 + kqs];
#pragma unroll
    for (int j = 0; j < JN; ++j)
      bf[j] = *(const short8*)&Bls[(wc + j * 16 + lm) * 32 + kqs];
#pragma unroll
    for (int i = 0; i < 4; ++i)
#pragma unroll
      for (int j = 0; j < JN; ++j)
        acc[i][j] = __builtin_amdgcn_mfma_f32_16x16x32_bf16(af[i], bf[j],
                                                            acc[i][j], 0, 0, 0);
  }

  float bb[JN];
#pragma unroll
  for (int j = 0; j < JN; ++j) bb[j] = bias[n0 + wc + j * 16 + lm];

#pragma unroll
  for (int i = 0; i < 4; ++i) {
#pragma unroll
    for (int r = 0; r < 4; ++r) {
      const int row = m0 + wr + i * 16 + rq + r;
      if (EPI == 1) {
        const float* resrow = res + (size_t)row * N + n0 + wc;
        float* crow = (float*)Cout + (size_t)row * N + n0 + wc;
#pragma unroll
        for (int j = 0; j < JN; ++j) {
          float rv = __builtin_nontemporal_load(resrow + j * 16 + lm);
          crow[j * 16 + lm] = acc[i][j][r] + bb[j] + rv;
        }
      } else if (EPI == 3) {
        const int bb_ = row >> 8, tt = row & 255;
#pragma unroll
        for (int j = 0; j < JN; ++j) {
          const int colb = n0 + wc + j * 16;
          const int sec = colb / 384, cc = colb % 384;
          const int hh = cc >> 6, db = (cc & 63) + lm;
          ushort* dstp = (sec == 0) ? (ushort*)Cout
                       : (sec == 1) ? (ushort*)C2 : (ushort*)C3;
          dstp[((size_t)(bb_ * Hh + hh) * Tseq + tt) * HSd + db] =
              f2bf(acc[i][j][r] + bb[j]);
        }
      } else {
        ushort* crow = (ushort*)Cout + (size_t)row * N + n0 + wc;
#pragma unroll
        for (int j = 0; j < JN; ++j) {
          float v = acc[i][j][r] + bb[j];
          if (EPI == 2) v = gelu_fast(v);
          crow[j * 16 + lm] = f2bf(v);
        }
      }
    }
  }
}

// ---------------------------------------------------------------------------
// MFMA flash attention. Block = (b*H+h, q-tile of 64 rows), 4 waves; wave w
// owns a 16-row Q strip. LDS stride 72 ushorts -> conflict-free frag reads.
// V transposed into LDS during staging. Output Oc bf16 [M][384] concat.
// ---------------------------------------------------------------------------
__global__ __launch_bounds__(256) void attn_kernel(
    const ushort* __restrict__ Qb, const ushort* __restrict__ Kb,
    const ushort* __restrict__ Vb, ushort* __restrict__ Oc) {
  __shared__ ushort Ks[64 * 72];     // [key][dim]
  __shared__ ushort Vt[64 * 72];     // [dim][key]
  __shared__ ushort Pl[4][16 * 72];  // per-wave P strip [row][key]
  const int bh = blockIdx.x, qt = blockIdx.y;
  const int b = bh / Hh, h = bh % Hh;
  const int tid = threadIdx.x;
  const int w = tid >> 6, lane = tid & 63;
  const int g = lane >> 4, n16 = lane & 15;

  const ushort* qrow = Qb + ((size_t)bh * Tseq + qt * 64 + w * 16 + n16) * HSd;
  short8 qf0 = *(const short8*)(qrow + g * 8);
  short8 qf1 = *(const short8*)(qrow + 32 + g * 8);

  f32x4 oacc[4] = {};
  float m_r[4], l_r[4];
#pragma unroll
  for (int r = 0; r < 4; ++r) { m_r[r] = -1e30f; l_r[r] = 0.f; }

  const int t0 = qt * 64 + w * 16 + g * 4;

  const ushort* Ksrc = Kb + (size_t)bh * Tseq * HSd;
  const ushort* Vsrc = Vb + (size_t)bh * Tseq * HSd;

  for (int st = 0; st <= qt; ++st) {
    __syncthreads();
    for (int c = tid; c < 512; c += 256) {
      int kr = c >> 3, kc = (c & 7) * 8;
      *(uint4*)&Ks[kr * 72 + kc] =
          *(const uint4*)&Ksrc[(size_t)(st * 64 + kr) * HSd + kc];
      int vr = c & 63, vc = (c >> 6) * 8;
      uint4 vv = *(const uint4*)&Vsrc[(size_t)(st * 64 + vr) * HSd + vc];
      const ushort* pv = (const ushort*)&vv;
#pragma unroll
      for (int i = 0; i < 8; ++i) Vt[(vc + i) * 72 + vr] = pv[i];
    }
    __syncthreads();

    f32x4 s[4];
#pragma unroll
    for (int ct = 0; ct < 4; ++ct) {
      short8 kf0 = *(const short8*)&Ks[(ct * 16 + n16) * 72 + g * 8];
      short8 kf1 = *(const short8*)&Ks[(ct * 16 + n16) * 72 + 32 + g * 8];
      f32x4 z = {};
      z = __builtin_amdgcn_mfma_f32_16x16x32_bf16(qf0, kf0, z, 0, 0, 0);
      z = __builtin_amdgcn_mfma_f32_16x16x32_bf16(qf1, kf1, z, 0, 0, 0);
      s[ct] = z;
    }

#pragma unroll
    for (int ct = 0; ct < 4; ++ct) {
      const int s_col = st * 64 + ct * 16 + n16;
#pragma unroll
      for (int r = 0; r < 4; ++r) {
        float v = s[ct][r] * 0.125f;
        s[ct][r] = (s_col > t0 + r) ? -1e30f : v;
      }
    }

#pragma unroll
    for (int r = 0; r < 4; ++r) {
      float m = fmaxf(fmaxf(s[0][r], s[1][r]), fmaxf(s[2][r], s[3][r]));
      m = fmaxf(m, __shfl_xor(m, 1, 64));
      m = fmaxf(m, __shfl_xor(m, 2, 64));
      m = fmaxf(m, __shfl_xor(m, 4, 64));
      m = fmaxf(m, __shfl_xor(m, 8, 64));
      float mnew = fmaxf(m_r[r], m);
      float alpha = __expf(m_r[r] - mnew);
      m_r[r] = mnew;
      float ssum = 0.f;
#pragma unroll
      for (int ct = 0; ct < 4; ++ct) {
        float p = __expf(s[ct][r] - mnew);
        s[ct][r] = p;
        ssum += p;
      }
      ssum += __shfl_xor(ssum, 1, 64);
      ssum += __shfl_xor(ssum, 2, 64);
      ssum += __shfl_xor(ssum, 4, 64);
      ssum += __shfl_xor(ssum, 8, 64);
      l_r[r] = l_r[r] * alpha + ssum;
#pragma unroll
      for (int j = 0; j < 4; ++j) oacc[j][r] *= alpha;
    }

    ushort* pw = &Pl[w][0];
#pragma unroll
    for (int ct = 0; ct < 4; ++ct)
#pragma unroll
      for (int r = 0; r < 4; ++r)
        pw[(g * 4 + r) * 72 + ct * 16 + n16] = f2bf(s[ct][r]);

    short8 pf0 = *(const short8*)&pw[n16 * 72 + g * 8];
    short8 pf1 = *(const short8*)&pw[n16 * 72 + 32 + g * 8];
#pragma unroll
    for (int j = 0; j < 4; ++j) {
      short8 vf0 = *(const short8*)&Vt[(j * 16 + n16) * 72 + g * 8];
      short8 vf1 = *(const short8*)&Vt[(j * 16 + n16) * 72 + 32 + g * 8];
      oacc[j] = __builtin_amdgcn_mfma_f32_16x16x32_bf16(pf0, vf0, oacc[j], 0, 0, 0);
      oacc[j] = __builtin_amdgcn_mfma_f32_16x16x32_bf16(pf1, vf1, oacc[j], 0, 0, 0);
    }
  }

  float inv[4];
#pragma unroll
  for (int r = 0; r < 4; ++r) inv[r] = 1.f / l_r[r];
  ushort* orow = Oc + ((size_t)(b * Tseq + qt * 64 + w * 16)) * Cdim + h * HSd;
#pragma unroll
  for (int j = 0; j < 4; ++j)
#pragma unroll
    for (int r = 0; r < 4; ++r)
      orow[(size_t)(g * 4 + r) * Cdim + j * 16 + n16] = f2bf(oacc[j][r] * inv[r]);
}

// ---------------------------------------------------------------------------
extern "C" void kernel_launch(void* const* d_in, const int* in_sizes, int n_in,
                              void* d_out, int out_size, void* d_ws, size_t ws_size,
                              hipStream_t stream) {
  const float* x      = (const float*)d_in[0];
  const float* ln1_w  = (const float*)d_in[1];
  const float* ln1_b  = (const float*)d_in[2];
  const float* Wq     = (const float*)d_in[3];
  const float* bq     = (const float*)d_in[4];
  const float* Wk     = (const float*)d_in[5];
  const float* bk     = (const float*)d_in[6];
  const float* Wv     = (const float*)d_in[7];
  const float* bv     = (const float*)d_in[8];
  const float* Wproj  = (const float*)d_in[9];
  const float* bproj  = (const float*)d_in[10];
  const float* ln2_w  = (const float*)d_in[11];
  const float* ln2_b  = (const float*)d_in[12];
  const float* W1     = (const float*)d_in[13];
  const float* b1     = (const float*)d_in[14];
  const float* W2     = (const float*)d_in[15];
  const float* b2     = (const float*)d_in[16];
  float* out = (float*)d_out;

  // Workspace layout (~117 MB)
  char* p = (char*)d_ws;
  ushort* h     = (ushort*)p;  p += (size_t)Mrows * Cdim * 2;   // reused as h2
  ushort* Qb    = (ushort*)p;                                    // 12.6 MB
  float*  x1    = (float*)p;   p += (size_t)Mrows * HSd * Hh * 2;  // aliases Qb+Kb
  ushort* Kb    = (ushort*)p;  p += (size_t)Mrows * HSd * Hh * 2;
  ushort* Vb    = (ushort*)p;  p += (size_t)Mrows * HSd * Hh * 2;
  ushort* Oc    = (ushort*)p;  p += (size_t)Mrows * Cdim * 2;
  ushort* g     = (ushort*)p;  p += (size_t)Mrows * Cffn * 2;
  ushort* WqkvT = (ushort*)p;  p += (size_t)Nqkv * Cdim * 2;
  ushort* WprojT= (ushort*)p;  p += (size_t)Cdim * Cdim * 2;
  ushort* W1T   = (ushort*)p;  p += (size_t)Cffn * Cdim * 2;
  ushort* W2T   = (ushort*)p;  p += (size_t)Cdim * Cffn * 2;
  float*  bqkv  = (float*)p;   p += (size_t)Nqkv * 4;
  ushort* h2 = h;

  dim3 blk(256);

  // 0. Fused weight prep (transpose-casts + bias concat), one launch
  prep_kernel<<<dim3(1733), blk, 0, stream>>>(Wq, Wk, Wv, Wproj, W1, W2,
                                              bq, bk, bv,
                                              WqkvT, WprojT, W1T, W2T, bqkv);

  // 1. LN1 -> h (bf16)
  ln_kernel<<<dim3(Mrows / 4), blk, 0, stream>>>(x, ln1_w, ln1_b, h, Mrows);

  // 2. QKV fused GEMM, epilogue splits Q/K/V into [BH][T][64] (coalesced)
  mfma_gemm<3, 128><<<dim3(Nqkv / 128, Mrows / 128), blk, 0, stream>>>(
      h, WqkvT, bqkv, nullptr, Qb, Kb, Vb, Mrows, Nqkv, Cdim);

  // 3. MFMA flash attention -> Oc (bf16, concat layout)
  attn_kernel<<<dim3(Bsz * Hh, 4), blk, 0, stream>>>(Qb, Kb, Vb, Oc);

  // 4. x1 = x + Oc @ Wproj + bproj (fp32) — skinny N: BN=64, 768 blocks
  mfma_gemm<1, 64><<<dim3(Cdim / 64, Mrows / 128), blk, 0, stream>>>(
      Oc, WprojT, bproj, x, x1, nullptr, nullptr, Mrows, Cdim, Cdim);

  // 5. LN2 -> h2 (bf16)
  ln_kernel<<<dim3(Mrows / 4), blk, 0, stream>>>(x1, ln2_w, ln2_b, h2, Mrows);

  // 6. g = gelu(h2 @ W1 + b1) (bf16)
  mfma_gemm<2, 128><<<dim3(Cffn / 128, Mrows / 128), blk, 0, stream>>>(
      h2, W1T, b1, nullptr, g, nullptr, nullptr, Mrows, Cffn, Cdim);

  // 7. out = x1 + g @ W2 + b2 (fp32) — skinny N: BN=64, 768 blocks
  mfma_gemm<1, 64><<<dim3(Cdim / 64, Mrows / 128), blk, 0, stream>>>(
      g, W2T, b2, x1, out, nullptr, nullptr, Mrows, Cdim, Cffn);
}

// Round 9
// 252.964 us; speedup vs baseline: 1.1390x; 1.0383x over previous
//
#include <hip/hip_runtime.h>
#include <math.h>

// Problem constants
constexpr int Bsz  = 64;
constexpr int Tseq = 256;
constexpr int Cdim = 384;
constexpr int Hh   = 6;
constexpr int HSd  = 64;
constexpr int Mrows = Bsz * Tseq;        // 16384
constexpr int Cffn  = 4 * Cdim;          // 1536
constexpr int Nqkv  = 3 * Cdim;          // 1152

typedef __attribute__((ext_vector_type(8))) short short8;  // 8 bf16 = 4 VGPRs
typedef __attribute__((ext_vector_type(4))) float f32x4;

// fp32 -> bf16 round-to-nearest-even
__device__ __forceinline__ ushort f2bf(float x) {
  union { float f; uint u; } a; a.f = x;
  uint r = a.u + 0x7fffu + ((a.u >> 16) & 1u);
  return (ushort)(r >> 16);
}
__device__ __forceinline__ float bf2f(ushort u) {
  union { uint u; float f; } a; a.u = ((uint)u) << 16;
  return a.f;
}

// Fast GELU (tanh form): ~3e-4 max error vs exact-erf, ~8 VALU ops vs ~25.
__device__ __forceinline__ float gelu_fast(float x) {
  float t = x * x;
  float u = x * fmaf(0.044715f, t, 1.0f);
  float e = fminf(1.5957691216f * u, 80.f);
  float z = __expf(e);
  return x * (z / (1.0f + z));
}

// ---------------------------------------------------------------------------
// Fused prep: all weight transpose-casts (fp32 [R][S] -> bf16 [S][R]) + bias
// concat, one launch. Blocks 0..1727 = 32x32 transpose tiles; 1728..1732 bias.
// ---------------------------------------------------------------------------
__global__ __launch_bounds__(256) void prep_kernel(
    const float* __restrict__ Wq, const float* __restrict__ Wk,
    const float* __restrict__ Wv, const float* __restrict__ Wproj,
    const float* __restrict__ W1, const float* __restrict__ W2,
    const float* __restrict__ bq, const float* __restrict__ bk,
    const float* __restrict__ bv,
    ushort* __restrict__ WqkvT, ushort* __restrict__ WprojT,
    ushort* __restrict__ W1T, ushort* __restrict__ W2T,
    float* __restrict__ bqkv) {
  const int bid = blockIdx.x;
  if (bid >= 1728) {  // bias concat
    int i = (bid - 1728) * 256 + threadIdx.x;
    if (i < Nqkv)
      bqkv[i] = (i < 384) ? bq[i] : (i < 768) ? bk[i - 384] : bv[i - 768];
    return;
  }
  const int tx = threadIdx.x & 31, ty = threadIdx.x >> 5;  // 32 x 8
  const float* src; ushort* dst; int R, S, r0, s0;
  if (bid < 432) {           // Wq/Wk/Wv: [6][384][64] each -> rows of WqkvT
    int which = bid / 144, rem = bid % 144;
    const float* W = (which == 0) ? Wq : (which == 1) ? Wk : Wv;
    int bz = rem / 24, t = rem % 24;
    R = 384; S = 64;
    src = W + (size_t)bz * R * S;
    dst = WqkvT + (size_t)which * 384 * 384 + (size_t)bz * R * S;
    r0 = (t >> 1) * 32; s0 = (t & 1) * 32;
  } else if (bid < 576) {    // Wproj 384x384
    int rem = bid - 432; R = 384; S = 384; src = Wproj; dst = WprojT;
    r0 = (rem / 12) * 32; s0 = (rem % 12) * 32;
  } else if (bid < 1152) {   // W1 384x1536
    int rem = bid - 576; R = 384; S = 1536; src = W1; dst = W1T;
    r0 = (rem / 48) * 32; s0 = (rem % 48) * 32;
  } else {                   // W2 1536x384
    int rem = bid - 1152; R = 1536; S = 384; src = W2; dst = W2T;
    r0 = (rem / 12) * 32; s0 = (rem % 12) * 32;
  }
  __shared__ float t[32][33];
#pragma unroll
  for (int i = 0; i < 32; i += 8)
    t[ty + i][tx] = src[(size_t)(r0 + ty + i) * S + s0 + tx];
  __syncthreads();
#pragma unroll
  for (int i = 0; i < 32; i += 8)
    dst[(size_t)(s0 + ty + i) * R + r0 + tx] = f2bf(t[tx][ty + i]);
}

// ---------------------------------------------------------------------------
// LayerNorm: one wave per row of 384; 4 rows per block. bf16 output.
// T = float (LN1 on x) or ushort (LN2 on bf16 x1).
// ---------------------------------------------------------------------------
template <typename T>
__global__ __launch_bounds__(256) void ln_kernel(
    const T* __restrict__ x, const float* __restrict__ w,
    const float* __restrict__ b, ushort* __restrict__ out, int nrows) {
  int row  = blockIdx.x * 4 + (threadIdx.x >> 6);
  int lane = threadIdx.x & 63;
  if (row >= nrows) return;
  const T* xr = x + (size_t)row * Cdim;
  float v[6];
  float s = 0.f;
#pragma unroll
  for (int i = 0; i < 6; ++i) {
    if constexpr (sizeof(T) == 2) v[i] = bf2f(xr[lane + 64 * i]);
    else                          v[i] = xr[lane + 64 * i];
    s += v[i];
  }
#pragma unroll
  for (int off = 32; off > 0; off >>= 1) s += __shfl_xor(s, off, 64);
  float mean = s * (1.f / Cdim);
  float sq = 0.f;
#pragma unroll
  for (int i = 0; i < 6; ++i) { float d = v[i] - mean; sq += d * d; }
#pragma unroll
  for (int off = 32; off > 0; off >>= 1) sq += __shfl_xor(sq, off, 64);
  float rstd = rsqrtf(sq * (1.f / Cdim) + 1e-5f);
  ushort* orow = out + (size_t)row * Cdim;
#pragma unroll
  for (int i = 0; i < 6; ++i) {
    int c = lane + 64 * i;
    orow[c] = f2bf((v[i] - mean) * rstd * w[c] + b[c]);
  }
}

// ---------------------------------------------------------------------------
// bf16 MFMA GEMM: C[M,N] = epi(A[M,K] @ Bt[N,K]^T + bias). 128xBN tile,
// BK=64 (R8->R9: halves barrier count; 8 global_load_lds in flight per
// barrier = 32 KB/block, doubling outstanding bytes — all GEMMs sustained
// only ~1.4 TB/s because loads drained at every barrier).
// LDS [row][64] with XOR chunk swizzle slot=(c&7)^(row&7); readers use
// quad (half*4+g)^(lm&7) -> all 8 bank-quads, 2-way (free, m136).
// XCD swizzle (R6, verified FETCH 51.7->10.9 MB). gridDim.y==128 required.
// No nontemporal stores (R6: 2.2x write amplification).
// EPI: 1 = +bias+res(fp32) -> bf16 (proj -> x1)
//      2 = gelu -> bf16 (FFN1 -> g)
//      3 = QKV split: Q,K,V each -> [BH][T][64] bf16
//      4 = +bias+res(bf16) -> fp32 (FFN2 -> out)
// ---------------------------------------------------------------------------
template <int EPI, int BN>
__global__ __launch_bounds__(256) void mfma_gemm(
    const ushort* __restrict__ A, const ushort* __restrict__ Bt,
    const float* __restrict__ bias, const void* __restrict__ res,
    void* __restrict__ Cout, void* __restrict__ C2, void* __restrict__ C3,
    int M, int N, int K) {
  constexpr int WC = BN / 2;    // wave col span
  constexpr int JN = WC / 16;   // col frags per wave (4 or 2)
  constexpr int NB = BN / 32;   // B staging chunks per thread (4 or 2)
  __shared__ ushort Als[128 * 64];
  __shared__ ushort Bls[BN * 64];
  const int tid = threadIdx.x;

  // XCD-aware remap (requires gridDim.y == 128)
  const int lid = blockIdx.y * gridDim.x + blockIdx.x;
  const int xcd = lid & 7, idx = lid >> 3;
  const int by = xcd * 16 + (idx & 15);
  const int bx = idx >> 4;
  const int m0 = by * 128, n0 = bx * BN;

  const int lane = tid & 63;
  const int w    = tid >> 6;
  const int wr   = (w >> 1) * 64;
  const int wc   = (w & 1) * WC;
  const int lm   = lane & 15;
  const int g    = lane >> 4;
  const int rq   = g * 4;

  const int wub = (tid & ~63) * 8;  // wave-uniform ushort offset of lane 0

  f32x4 acc[4][JN] = {};

  for (int k0 = 0; k0 < K; k0 += 64) {
    __syncthreads();
#pragma unroll
    for (int q = 0; q < 4; ++q) {    // A: 128 rows x 8 chunks = 1024
      const int ci = tid + q * 256;
      const int row = ci >> 3;
      const int kc = ((ci & 7) ^ (row & 7)) * 8;
      const ushort* gA = A + (size_t)(m0 + row) * K + k0 + kc;
      __builtin_amdgcn_global_load_lds(
          (const __attribute__((address_space(1))) uint*)gA,
          (__attribute__((address_space(3))) uint*)(Als + wub + q * 2048),
          16, 0, 0);
    }
#pragma unroll
    for (int q = 0; q < NB; ++q) {   // B: BN rows x 8 chunks
      const int ci = tid + q * 256;
      const int row = ci >> 3;
      const int kc = ((ci & 7) ^ (row & 7)) * 8;
      const ushort* gB = Bt + (size_t)(n0 + row) * K + k0 + kc;
      __builtin_amdgcn_global_load_lds(
          (const __attribute__((address_space(1))) uint*)gB,
          (__attribute__((address_space(3))) uint*)(Bls + wub + q * 2048),
          16, 0, 0);
    }
    __syncthreads();

#pragma unroll
    for (int half = 0; half < 2; ++half) {
      const int sl = ((half << 2) | g) ^ (lm & 7);  // swizzled chunk slot
      short8 af[4], bf[JN];
#pragma unroll
      for (int i = 0; i < 4; ++i)
        af[i] = *(const short8*)&Als[(wr + i * 16 + lm) * 64 + sl * 8];
#pragma unroll
      for (int j = 0; j < JN; ++j)
        bf[j] = *(const short8*)&Bls[(wc + j * 16 + lm) * 64 + sl * 8];
#pragma unroll
      for (int i = 0; i < 4; ++i)
#pragma unroll
        for (int j = 0; j < JN; ++j)
          acc[i][j] = __builtin_amdgcn_mfma_f32_16x16x32_bf16(af[i], bf[j],
                                                              acc[i][j], 0, 0, 0);
    }
  }

  float bb[JN];
#pragma unroll
  for (int j = 0; j < JN; ++j) bb[j] = bias[n0 + wc + j * 16 + lm];

#pragma unroll
  for (int i = 0; i < 4; ++i) {
#pragma unroll
    for (int r = 0; r < 4; ++r) {
      const int row = m0 + wr + i * 16 + rq + r;
      if (EPI == 1) {        // + fp32 residual -> bf16 out
        const float* resrow = (const float*)res + (size_t)row * N + n0 + wc;
        ushort* crow = (ushort*)Cout + (size_t)row * N + n0 + wc;
#pragma unroll
        for (int j = 0; j < JN; ++j) {
          float rv = __builtin_nontemporal_load(resrow + j * 16 + lm);
          crow[j * 16 + lm] = f2bf(acc[i][j][r] + bb[j] + rv);
        }
      } else if (EPI == 4) { // + bf16 residual -> fp32 out
        const ushort* resrow = (const ushort*)res + (size_t)row * N + n0 + wc;
        float* crow = (float*)Cout + (size_t)row * N + n0 + wc;
#pragma unroll
        for (int j = 0; j < JN; ++j)
          crow[j * 16 + lm] = acc[i][j][r] + bb[j] + bf2f(resrow[j * 16 + lm]);
      } else if (EPI == 3) {
        const int bb_ = row >> 8, tt = row & 255;
#pragma unroll
        for (int j = 0; j < JN; ++j) {
          const int colb = n0 + wc + j * 16;
          const int sec = colb / 384, cc = colb % 384;
          const int hh = cc >> 6, db = (cc & 63) + lm;
          ushort* dstp = (sec == 0) ? (ushort*)Cout
                       : (sec == 1) ? (ushort*)C2 : (ushort*)C3;
          dstp[((size_t)(bb_ * Hh + hh) * Tseq + tt) * HSd + db] =
              f2bf(acc[i][j][r] + bb[j]);
        }
      } else {               // EPI == 2: gelu -> bf16
        ushort* crow = (ushort*)Cout + (size_t)row * N + n0 + wc;
#pragma unroll
        for (int j = 0; j < JN; ++j)
          crow[j * 16 + lm] = f2bf(gelu_fast(acc[i][j][r] + bb[j]));
      }
    }
  }
}

// ---------------------------------------------------------------------------
// MFMA flash attention. Block = (b*H+h, q-tile of 64 rows), 4 waves; wave w
// owns a 16-row Q strip. LDS stride 72 ushorts -> conflict-free frag reads.
// V transposed into LDS during staging. Output Oc bf16 [M][384] concat.
// ---------------------------------------------------------------------------
__global__ __launch_bounds__(256) void attn_kernel(
    const ushort* __restrict__ Qb, const ushort* __restrict__ Kb,
    const ushort* __restrict__ Vb, ushort* __restrict__ Oc) {
  __shared__ ushort Ks[64 * 72];     // [key][dim]
  __shared__ ushort Vt[64 * 72];     // [dim][key]
  __shared__ ushort Pl[4][16 * 72];  // per-wave P strip [row][key]
  const int bh = blockIdx.x, qt = blockIdx.y;
  const int b = bh / Hh, h = bh % Hh;
  const int tid = threadIdx.x;
  const int w = tid >> 6, lane = tid & 63;
  const int g = lane >> 4, n16 = lane & 15;

  const ushort* qrow = Qb + ((size_t)bh * Tseq + qt * 64 + w * 16 + n16) * HSd;
  short8 qf0 = *(const short8*)(qrow + g * 8);
  short8 qf1 = *(const short8*)(qrow + 32 + g * 8);

  f32x4 oacc[4] = {};
  float m_r[4], l_r[4];
#pragma unroll
  for (int r = 0; r < 4; ++r) { m_r[r] = -1e30f; l_r[r] = 0.f; }

  const int t0 = qt * 64 + w * 16 + g * 4;

  const ushort* Ksrc = Kb + (size_t)bh * Tseq * HSd;
  const ushort* Vsrc = Vb + (size_t)bh * Tseq * HSd;

  for (int st = 0; st <= qt; ++st) {
    __syncthreads();
    for (int c = tid; c < 512; c += 256) {
      int kr = c >> 3, kc = (c & 7) * 8;
      *(uint4*)&Ks[kr * 72 + kc] =
          *(const uint4*)&Ksrc[(size_t)(st * 64 + kr) * HSd + kc];
      int vr = c & 63, vc = (c >> 6) * 8;
      uint4 vv = *(const uint4*)&Vsrc[(size_t)(st * 64 + vr) * HSd + vc];
      const ushort* pv = (const ushort*)&vv;
#pragma unroll
      for (int i = 0; i < 8; ++i) Vt[(vc + i) * 72 + vr] = pv[i];
    }
    __syncthreads();

    f32x4 s[4];
#pragma unroll
    for (int ct = 0; ct < 4; ++ct) {
      short8 kf0 = *(const short8*)&Ks[(ct * 16 + n16) * 72 + g * 8];
      short8 kf1 = *(const short8*)&Ks[(ct * 16 + n16) * 72 + 32 + g * 8];
      f32x4 z = {};
      z = __builtin_amdgcn_mfma_f32_16x16x32_bf16(qf0, kf0, z, 0, 0, 0);
      z = __builtin_amdgcn_mfma_f32_16x16x32_bf16(qf1, kf1, z, 0, 0, 0);
      s[ct] = z;
    }

#pragma unroll
    for (int ct = 0; ct < 4; ++ct) {
      const int s_col = st * 64 + ct * 16 + n16;
#pragma unroll
      for (int r = 0; r < 4; ++r) {
        float v = s[ct][r] * 0.125f;
        s[ct][r] = (s_col > t0 + r) ? -1e30f : v;
      }
    }

#pragma unroll
    for (int r = 0; r < 4; ++r) {
      float m = fmaxf(fmaxf(s[0][r], s[1][r]), fmaxf(s[2][r], s[3][r]));
      m = fmaxf(m, __shfl_xor(m, 1, 64));
      m = fmaxf(m, __shfl_xor(m, 2, 64));
      m = fmaxf(m, __shfl_xor(m, 4, 64));
      m = fmaxf(m, __shfl_xor(m, 8, 64));
      float mnew = fmaxf(m_r[r], m);
      float alpha = __expf(m_r[r] - mnew);
      m_r[r] = mnew;
      float ssum = 0.f;
#pragma unroll
      for (int ct = 0; ct < 4; ++ct) {
        float p = __expf(s[ct][r] - mnew);
        s[ct][r] = p;
        ssum += p;
      }
      ssum += __shfl_xor(ssum, 1, 64);
      ssum += __shfl_xor(ssum, 2, 64);
      ssum += __shfl_xor(ssum, 4, 64);
      ssum += __shfl_xor(ssum, 8, 64);
      l_r[r] = l_r[r] * alpha + ssum;
#pragma unroll
      for (int j = 0; j < 4; ++j) oacc[j][r] *= alpha;
    }

    ushort* pw = &Pl[w][0];
#pragma unroll
    for (int ct = 0; ct < 4; ++ct)
#pragma unroll
      for (int r = 0; r < 4; ++r)
        pw[(g * 4 + r) * 72 + ct * 16 + n16] = f2bf(s[ct][r]);

    short8 pf0 = *(const short8*)&pw[n16 * 72 + g * 8];
    short8 pf1 = *(const short8*)&pw[n16 * 72 + 32 + g * 8];
#pragma unroll
    for (int j = 0; j < 4; ++j) {
      short8 vf0 = *(const short8*)&Vt[(j * 16 + n16) * 72 + g * 8];
      short8 vf1 = *(const short8*)&Vt[(j * 16 + n16) * 72 + 32 + g * 8];
      oacc[j] = __builtin_amdgcn_mfma_f32_16x16x32_bf16(pf0, vf0, oacc[j], 0, 0, 0);
      oacc[j] = __builtin_amdgcn_mfma_f32_16x16x32_bf16(pf1, vf1, oacc[j], 0, 0, 0);
    }
  }

  float inv[4];
#pragma unroll
  for (int r = 0; r < 4; ++r) inv[r] = 1.f / l_r[r];
  ushort* orow = Oc + ((size_t)(b * Tseq + qt * 64 + w * 16)) * Cdim + h * HSd;
#pragma unroll
  for (int j = 0; j < 4; ++j)
#pragma unroll
    for (int r = 0; r < 4; ++r)
      orow[(size_t)(g * 4 + r) * Cdim + j * 16 + n16] = f2bf(oacc[j][r] * inv[r]);
}

// ---------------------------------------------------------------------------
extern "C" void kernel_launch(void* const* d_in, const int* in_sizes, int n_in,
                              void* d_out, int out_size, void* d_ws, size_t ws_size,
                              hipStream_t stream) {
  const float* x      = (const float*)d_in[0];
  const float* ln1_w  = (const float*)d_in[1];
  const float* ln1_b  = (const float*)d_in[2];
  const float* Wq     = (const float*)d_in[3];
  const float* bq     = (const float*)d_in[4];
  const float* Wk     = (const float*)d_in[5];
  const float* bk     = (const float*)d_in[6];
  const float* Wv     = (const float*)d_in[7];
  const float* bv     = (const float*)d_in[8];
  const float* Wproj  = (const float*)d_in[9];
  const float* bproj  = (const float*)d_in[10];
  const float* ln2_w  = (const float*)d_in[11];
  const float* ln2_b  = (const float*)d_in[12];
  const float* W1     = (const float*)d_in[13];
  const float* b1     = (const float*)d_in[14];
  const float* W2     = (const float*)d_in[15];
  const float* b2     = (const float*)d_in[16];
  float* out = (float*)d_out;

  // Workspace layout (~115 MB). x1 is bf16 now and aliases Qb (dead after attn).
  char* p = (char*)d_ws;
  ushort* h     = (ushort*)p;  p += (size_t)Mrows * Cdim * 2;   // reused as h2
  ushort* Qb    = (ushort*)p;  p += (size_t)Mrows * Cdim * 2;   // x1 aliases
  ushort* Kb    = (ushort*)p;  p += (size_t)Mrows * Cdim * 2;
  ushort* Vb    = (ushort*)p;  p += (size_t)Mrows * Cdim * 2;
  ushort* Oc    = (ushort*)p;  p += (size_t)Mrows * Cdim * 2;
  ushort* g     = (ushort*)p;  p += (size_t)Mrows * Cffn * 2;
  ushort* WqkvT = (ushort*)p;  p += (size_t)Nqkv * Cdim * 2;
  ushort* WprojT= (ushort*)p;  p += (size_t)Cdim * Cdim * 2;
  ushort* W1T   = (ushort*)p;  p += (size_t)Cffn * Cdim * 2;
  ushort* W2T   = (ushort*)p;  p += (size_t)Cdim * Cffn * 2;
  float*  bqkv  = (float*)p;   p += (size_t)Nqkv * 4;
  ushort* h2 = h;
  ushort* x1 = Qb;

  dim3 blk(256);

  // 0. Fused weight prep (transpose-casts + bias concat), one launch
  prep_kernel<<<dim3(1733), blk, 0, stream>>>(Wq, Wk, Wv, Wproj, W1, W2,
                                              bq, bk, bv,
                                              WqkvT, WprojT, W1T, W2T, bqkv);

  // 1. LN1 -> h (bf16)
  ln_kernel<float><<<dim3(Mrows / 4), blk, 0, stream>>>(x, ln1_w, ln1_b, h, Mrows);

  // 2. QKV fused GEMM, epilogue splits Q/K/V into [BH][T][64] (coalesced)
  mfma_gemm<3, 128><<<dim3(Nqkv / 128, Mrows / 128), blk, 0, stream>>>(
      h, WqkvT, bqkv, nullptr, Qb, Kb, Vb, Mrows, Nqkv, Cdim);

  // 3. MFMA flash attention -> Oc (bf16, concat layout)
  attn_kernel<<<dim3(Bsz * Hh, 4), blk, 0, stream>>>(Qb, Kb, Vb, Oc);

  // 4. x1 = x + Oc @ Wproj + bproj -> bf16 (skinny N: BN=64)
  mfma_gemm<1, 64><<<dim3(Cdim / 64, Mrows / 128), blk, 0, stream>>>(
      Oc, WprojT, bproj, x, x1, nullptr, nullptr, Mrows, Cdim, Cdim);

  // 5. LN2 -> h2 (bf16, reads bf16 x1)
  ln_kernel<ushort><<<dim3(Mrows / 4), blk, 0, stream>>>(x1, ln2_w, ln2_b, h2, Mrows);

  // 6. g = gelu(h2 @ W1 + b1) (bf16)
  mfma_gemm<2, 128><<<dim3(Cffn / 128, Mrows / 128), blk, 0, stream>>>(
      h2, W1T, b1, nullptr, g, nullptr, nullptr, Mrows, Cffn, Cdim);

  // 7. out = x1 + g @ W2 + b2 -> fp32 (bf16 residual; skinny N: BN=64)
  mfma_gemm<4, 64><<<dim3(Cdim / 64, Mrows / 128), blk, 0, stream>>>(
      g, W2T, b2, x1, out, nullptr, nullptr, Mrows, Cdim, Cffn);
}